// Round 2
// baseline (238.918 us; speedup 1.0000x reference)
//
#include <hip/hip_runtime.h>
#include <hip/hip_bf16.h>

// Problem constants
constexpr int B      = 16384;
constexpr int D_IN   = 1024;
constexpr int D_OUT  = 256;
constexpr int NCLS   = 1000;
constexpr int CPAD   = 1024;   // padded class count

// ---------------- workspace layout (byte offsets) ----------------
constexpr size_t OFF_XB   = 0;                                    // B*D_IN bf16   (32 MB)
constexpr size_t OFF_WB   = OFF_XB  + (size_t)B * D_IN * 2;       // 512*D_IN bf16 (1 MB)
constexpr size_t OFF_S    = OFF_WB  + (size_t)512 * D_IN * 2;     // CPAD*D_IN f32 (4 MB)
constexpr size_t OFF_Z    = OFF_S   + (size_t)CPAD * D_IN * 4;    // CPAD*D_OUT f32 (1 MB, zeroed)
constexpr size_t OFF_T    = OFF_Z   + (size_t)CPAD * D_OUT * 4;   // D_IN f32 (zeroed)
constexpr size_t OFF_CNT  = OFF_T   + (size_t)D_IN * 4;           // CPAD int
constexpr size_t OFF_OFFS = OFF_CNT + (size_t)CPAD * 4;           // CPAD int
constexpr size_t OFF_CUR  = OFF_OFFS+ (size_t)CPAD * 4;           // CPAD int (unused now)
constexpr size_t OFF_ROWL = OFF_CUR + (size_t)CPAD * 4;           // B int

typedef short bf16x8 __attribute__((ext_vector_type(8)));
typedef float f32x4  __attribute__((ext_vector_type(4)));

// fp32 -> bf16 round-to-nearest-even
__device__ __forceinline__ unsigned short f2bf(float f) {
    unsigned int u = __float_as_uint(f);
    return (unsigned short)((u + 0x7FFFu + ((u >> 16) & 1u)) >> 16);
}

__device__ __forceinline__ void cvt8(const float4& a, const float4& b, unsigned short* dst) {
    union { unsigned short u[8]; bf16x8 v; } r;
    r.u[0] = f2bf(a.x); r.u[1] = f2bf(a.y); r.u[2] = f2bf(a.z); r.u[3] = f2bf(a.w);
    r.u[4] = f2bf(b.x); r.u[5] = f2bf(b.y); r.u[6] = f2bf(b.z); r.u[7] = f2bf(b.w);
    *(bf16x8*)dst = r.v;
}

__device__ __forceinline__ ushort4 f2bf4(const float4& a) {
    ushort4 r;
    r.x = f2bf(a.x); r.y = f2bf(a.y); r.z = f2bf(a.z); r.w = f2bf(a.w);
    return r;
}

// async global->LDS, 16B/lane; lds dst = wave-uniform base (+lane*16 implied by HW)
__device__ __forceinline__ void async16(const unsigned short* g, unsigned short* l) {
    __builtin_amdgcn_global_load_lds(
        (const __attribute__((address_space(1))) void*)g,
        (__attribute__((address_space(3))) void*)l,
        16, 0, 0);
}

// ---- 1. fused prep: blocks 0..63 convert W1,W2->bf16 + zero T,Z;
//         block 64 does hist+scan+scatter (counting sort) entirely in one block ----
__global__ __launch_bounds__(1024)
void prep_kernel(const float* __restrict__ W1, const float* __restrict__ W2,
                 unsigned short* __restrict__ Wb,
                 float* __restrict__ T, float* __restrict__ Z,
                 const int* __restrict__ label,
                 int* __restrict__ cnt, int* __restrict__ offs,
                 int* __restrict__ rowlist) {
    __shared__ int hA[1024];
    __shared__ int hB[1024];

    if (blockIdx.x < 64) {
        int lin = blockIdx.x * 1024 + threadIdx.x;   // 0..65535
        int i = lin * 8;
        const float* src = (i < D_OUT * D_IN) ? (W1 + i) : (W2 + (i - D_OUT * D_IN));
        float4 a = *(const float4*)(src);
        float4 b = *(const float4*)(src + 4);
        cvt8(a, b, Wb + i);
        if (lin < D_IN) T[lin] = 0.f;
        *(float4*)(Z + (size_t)lin * 4) = float4{0.f, 0.f, 0.f, 0.f};  // 65536*4 floats = CPAD*D_OUT
        return;
    }

    // ---- block 64: single-block counting-sort prep ----
    int t = threadIdx.x;
    hA[t] = 0;
    __syncthreads();
    int lab[16];
#pragma unroll
    for (int r = 0; r < 16; ++r) {
        lab[r] = label[t + r * 1024];          // coalesced
        atomicAdd(&hA[lab[r]], 1);             // LDS histogram
    }
    __syncthreads();
    int v = hA[t];
    // Hillis-Steele inclusive scan, ping-pong
    int* src = hA;
    int* dst = hB;
    for (int off = 1; off < 1024; off <<= 1) {
        int sv = src[t];
        if (t >= off) sv += src[t - off];
        dst[t] = sv;
        __syncthreads();
        int* tmp = src; src = dst; dst = tmp;
    }
    int excl = src[t] - v;                     // exclusive prefix
    cnt[t]  = v;
    offs[t] = excl;
    dst[t]  = excl;                            // dst buffer = cursor
    __syncthreads();
#pragma unroll
    for (int r = 0; r < 16; ++r) {
        int p = atomicAdd(&dst[lab[r]], 1);
        rowlist[p] = t + r * 1024;
    }
}

// ---- 2. per-class fp32 column sums of x; emits xb = bf16(x); atomically folds T ----
__global__ void segsum_kernel(const float* __restrict__ x,
                              const int* __restrict__ offs,
                              const int* __restrict__ cnt,
                              const int* __restrict__ rowlist,
                              float* __restrict__ s,
                              unsigned short* __restrict__ xb,
                              float* __restrict__ T) {
    int c = blockIdx.x;            // 0..1023
    int col = threadIdx.x * 4;
    float4 acc = {0.f, 0.f, 0.f, 0.f};
    if (c < NCLS) {
        int o = offs[c], n = cnt[c];
        int r = 0;
        for (; r + 4 <= n; r += 4) {
            int i0 = rowlist[o + r + 0];
            int i1 = rowlist[o + r + 1];
            int i2 = rowlist[o + r + 2];
            int i3 = rowlist[o + r + 3];
            float4 v0 = *(const float4*)(x + (size_t)i0 * D_IN + col);
            float4 v1 = *(const float4*)(x + (size_t)i1 * D_IN + col);
            float4 v2 = *(const float4*)(x + (size_t)i2 * D_IN + col);
            float4 v3 = *(const float4*)(x + (size_t)i3 * D_IN + col);
            *(ushort4*)(xb + (size_t)i0 * D_IN + col) = f2bf4(v0);
            *(ushort4*)(xb + (size_t)i1 * D_IN + col) = f2bf4(v1);
            *(ushort4*)(xb + (size_t)i2 * D_IN + col) = f2bf4(v2);
            *(ushort4*)(xb + (size_t)i3 * D_IN + col) = f2bf4(v3);
            acc.x += (v0.x + v1.x) + (v2.x + v3.x);
            acc.y += (v0.y + v1.y) + (v2.y + v3.y);
            acc.z += (v0.z + v1.z) + (v2.z + v3.z);
            acc.w += (v0.w + v1.w) + (v2.w + v3.w);
        }
        for (; r < n; ++r) {
            int i0 = rowlist[o + r];
            float4 v = *(const float4*)(x + (size_t)i0 * D_IN + col);
            *(ushort4*)(xb + (size_t)i0 * D_IN + col) = f2bf4(v);
            acc.x += v.x; acc.y += v.y; acc.z += v.z; acc.w += v.w;
        }
    }
    *(float4*)(s + (size_t)c * D_IN + col) = acc;
    if (c < NCLS) {
        atomicAdd(&T[col + 0], acc.x);
        atomicAdd(&T[col + 1], acc.y);
        atomicAdd(&T[col + 2], acc.z);
        atomicAdd(&T[col + 3], acc.w);
    }
}

// ---- 3. Z[c] += ((T - s_c)/d_c) @ W2^T (+ b2 in chunk 0); 64x64 tile, K-split x4 ----
__global__ __launch_bounds__(256)
void meanz_kernel(const float* __restrict__ s,
                  const float* __restrict__ T,
                  const int* __restrict__ cnt,
                  const unsigned short* __restrict__ Wb,
                  const float* __restrict__ b2,
                  float* __restrict__ Z) {
    __shared__ unsigned short As[64 * 32];
    __shared__ unsigned short Bs[64 * 32];

    const int tid  = threadIdx.x;
    const int wave = tid >> 6;
    const int lane = tid & 63;
    const int quad = lane >> 4;
    const int l16  = lane & 15;
    const int bm   = blockIdx.x * 64;   // class base
    const int bn   = blockIdx.y * 64;   // out-col base
    const int kb   = blockIdx.z * 256;  // K chunk
    const int wm   = (wave >> 1) * 32;
    const int wn   = (wave & 1) * 32;

    const int arow = tid >> 2;          // 0..63
    const int akc  = (tid & 3) * 8;     // 0,8,16,24

    const int cls = bm + arow;
    const int d   = B - cnt[cls];
    const float scale = (d > 0) ? 1.f / (float)d : 0.f;
    const float* sp = s + (size_t)cls * D_IN + akc;
    const float* tp = T + akc;

    // B async chunk mapping: 1 chunk of 16B per thread
    const int bidx = wave * 64 + lane;
    const int brow = bidx >> 2;
    const int bkc  = (bidx & 3) * 8;
    const unsigned short* bp = Wb + (size_t)(256 + bn + brow) * D_IN + bkc;

    f32x4 acc[2][2] = {};

    for (int k0 = kb; k0 < kb + 256; k0 += 32) {
        float4 s0 = *(const float4*)(sp + k0);
        float4 s1 = *(const float4*)(sp + k0 + 4);
        float4 t0 = *(const float4*)(tp + k0);
        float4 t1 = *(const float4*)(tp + k0 + 4);
        __syncthreads();   // previous iteration's frag reads complete
        async16(bp + k0, Bs + wave * 512);
        float4 m0 = {(t0.x - s0.x) * scale, (t0.y - s0.y) * scale,
                     (t0.z - s0.z) * scale, (t0.w - s0.w) * scale};
        float4 m1 = {(t1.x - s1.x) * scale, (t1.y - s1.y) * scale,
                     (t1.z - s1.z) * scale, (t1.w - s1.w) * scale};
        cvt8(m0, m1, As + arow * 32 + akc);
        __syncthreads();   // drains vmcnt (async B) + lgkm (A writes)

        bf16x8 af[2], bfr[2];
#pragma unroll
        for (int t = 0; t < 2; ++t) {
            af[t]  = *(const bf16x8*)&As[(wm + t * 16 + l16) * 32 + quad * 8];
            bfr[t] = *(const bf16x8*)&Bs[(wn + t * 16 + l16) * 32 + quad * 8];
        }
#pragma unroll
        for (int i = 0; i < 2; ++i)
#pragma unroll
            for (int j = 0; j < 2; ++j)
                acc[i][j] = __builtin_amdgcn_mfma_f32_16x16x32_bf16(af[i], bfr[j], acc[i][j], 0, 0, 0);
    }

    const bool addb = (blockIdx.z == 0);
#pragma unroll
    for (int j = 0; j < 2; ++j) {
        const int n = bn + wn + j * 16 + l16;
        const float bias = addb ? b2[n] : 0.f;
#pragma unroll
        for (int i = 0; i < 2; ++i)
#pragma unroll
            for (int r = 0; r < 4; ++r) {
                const int c = bm + wm + i * 16 + quad * 4 + r;
                atomicAdd(&Z[(size_t)c * D_OUT + n], acc[i][j][r] + bias);
            }
    }
}

// ---- 4. out = xb @ W1b^T + b1 + Z[label] ; 128x64 tile, BK=64, all-async staging ----
// LDS holds the two K=32 slices in separate halves ([2][rows][32]) so the row
// stride stays 64 B => same conflict-free ds_read_b128 pattern as the 64x64 version.
__global__ __launch_bounds__(256)
void gemm1_kernel(const unsigned short* __restrict__ xb,
                  const unsigned short* __restrict__ Wb,
                  const float* __restrict__ b1,
                  const float* __restrict__ Z,
                  const int* __restrict__ label,
                  float* __restrict__ out) {
    __shared__ unsigned short As[2][128][32];   // 16 KB
    __shared__ unsigned short Bs[2][64][32];    //  8 KB

    const int tid  = threadIdx.x;
    const int wave = tid >> 6;
    const int lane = tid & 63;
    const int quad = lane >> 4;
    const int l16  = lane & 15;
    const int bm   = blockIdx.x * 128;
    const int bn   = blockIdx.y * 64;
    const int wm   = (wave >> 1) * 64;   // 2x2 wave grid: each wave owns 64x32
    const int wn   = (wave & 1) * 32;

    // A staging: 1024 chunks of 16B (4 rounds x 256 threads)
    //   chunk d: h=d>>9 (K-half), r=(d>>2)&127 (row), c=d&3 (16B col within half)
    const unsigned short* aps[4];
#pragma unroll
    for (int rr = 0; rr < 4; ++rr) {
        int dd = rr * 256 + tid;
        int h = dd >> 9, r = (dd >> 2) & 127, c = dd & 3;
        aps[rr] = xb + (size_t)(bm + r) * D_IN + h * 32 + c * 8;
    }
    // B staging: 512 chunks (2 rounds x 256 threads)
    const unsigned short* bps[2];
#pragma unroll
    for (int rr = 0; rr < 2; ++rr) {
        int dd = rr * 256 + tid;
        int h = dd >> 8, r = (dd >> 2) & 63, c = dd & 3;
        bps[rr] = Wb + (size_t)(bn + r) * D_IN + h * 32 + c * 8;
    }

    f32x4 acc[4][2] = {};

    for (int k0 = 0; k0 < D_IN; k0 += 64) {
        __syncthreads();   // previous iteration's frag reads complete
#pragma unroll
        for (int rr = 0; rr < 4; ++rr)
            async16(aps[rr] + k0, &As[0][0][0] + rr * 2048 + wave * 512);
#pragma unroll
        for (int rr = 0; rr < 2; ++rr)
            async16(bps[rr] + k0, &Bs[0][0][0] + rr * 2048 + wave * 512);
        __syncthreads();   // vmcnt drain before frag reads

#pragma unroll
        for (int ks = 0; ks < 2; ++ks) {
            bf16x8 af[4], bfr[2];
#pragma unroll
            for (int i = 0; i < 4; ++i)
                af[i] = *(const bf16x8*)&As[ks][wm + i * 16 + l16][quad * 8];
#pragma unroll
            for (int j = 0; j < 2; ++j)
                bfr[j] = *(const bf16x8*)&Bs[ks][wn + j * 16 + l16][quad * 8];
#pragma unroll
            for (int i = 0; i < 4; ++i)
#pragma unroll
                for (int j = 0; j < 2; ++j)
                    acc[i][j] = __builtin_amdgcn_mfma_f32_16x16x32_bf16(af[i], bfr[j], acc[i][j], 0, 0, 0);
        }
    }

    // epilogue: out[m][n] = acc + b1[n] + Z[label[m]][n]
    int zrow[4][4];
#pragma unroll
    for (int i = 0; i < 4; ++i)
#pragma unroll
        for (int r = 0; r < 4; ++r)
            zrow[i][r] = label[bm + wm + i * 16 + quad * 4 + r] * D_OUT;

#pragma unroll
    for (int j = 0; j < 2; ++j) {
        const int n = bn + wn + j * 16 + l16;
        const float bias = b1[n];
#pragma unroll
        for (int i = 0; i < 4; ++i)
#pragma unroll
            for (int r = 0; r < 4; ++r) {
                const int m = bm + wm + i * 16 + quad * 4 + r;
                out[(size_t)m * D_OUT + n] = acc[i][j][r] + bias + Z[zrow[i][r] + n];
            }
    }
}

// ---------------- launcher ----------------
extern "C" void kernel_launch(void* const* d_in, const int* in_sizes, int n_in,
                              void* d_out, int out_size, void* d_ws, size_t ws_size,
                              hipStream_t stream) {
    const float* x    = (const float*)d_in[0];
    const int*   lab  = (const int*)d_in[1];
    const float* W1_w = (const float*)d_in[2];
    const float* W1_b = (const float*)d_in[3];
    const float* W2_w = (const float*)d_in[4];
    const float* W2_b = (const float*)d_in[5];
    float* out = (float*)d_out;

    char* ws = (char*)d_ws;
    unsigned short* xb = (unsigned short*)(ws + OFF_XB);
    unsigned short* Wb = (unsigned short*)(ws + OFF_WB);
    float* s   = (float*)(ws + OFF_S);
    float* Z   = (float*)(ws + OFF_Z);
    float* T   = (float*)(ws + OFF_T);
    int* cnt     = (int*)(ws + OFF_CNT);
    int* offs    = (int*)(ws + OFF_OFFS);
    int* rowlist = (int*)(ws + OFF_ROWL);

    // 1. fused: W convert + zero T/Z (blocks 0-63) || hist+scan+scatter (block 64)
    prep_kernel<<<65, 1024, 0, stream>>>(W1_w, W2_w, Wb, T, Z, lab, cnt, offs, rowlist);
    // 2. per-class sums + xb emit + T fold
    segsum_kernel<<<CPAD, 256, 0, stream>>>(x, offs, cnt, rowlist, s, xb, T);
    // 3. Z table (K-split x4, 256 blocks)
    dim3 zgrid(CPAD / 64, D_OUT / 64, 4);
    meanz_kernel<<<zgrid, 256, 0, stream>>>(s, T, cnt, Wb, W2_b, Z);
    // 4. main GEMM, 128x64 tile, BK=64
    dim3 ggrid(B / 128, D_OUT / 64);
    gemm1_kernel<<<ggrid, 256, 0, stream>>>(xb, Wb, W1_b, Z, lab, out);
}

// Round 3
// 163.842 us; speedup vs baseline: 1.4582x; 1.4582x over previous
//
#include <hip/hip_runtime.h>
#include <hip/hip_bf16.h>

// Problem constants
constexpr int B      = 16384;
constexpr int D_IN   = 1024;
constexpr int D_OUT  = 256;
constexpr int NCLS   = 1000;
constexpr int CPAD   = 1024;   // padded class count

// ---------------- workspace layout (byte offsets) ----------------
constexpr size_t OFF_XB   = 0;                                    // B*D_IN bf16   (32 MB)
constexpr size_t OFF_WB   = OFF_XB  + (size_t)B * D_IN * 2;       // 512*D_IN bf16 (1 MB)
constexpr size_t OFF_S    = OFF_WB  + (size_t)512 * D_IN * 2;     // CPAD*D_IN f32 (4 MB)
constexpr size_t OFF_Z    = OFF_S   + (size_t)CPAD * D_IN * 4;    // CPAD*D_OUT f32 (1 MB, zeroed)
constexpr size_t OFF_T    = OFF_Z   + (size_t)CPAD * D_OUT * 4;   // D_IN f32 (zeroed)
constexpr size_t OFF_CNT  = OFF_T   + (size_t)D_IN * 4;           // CPAD int
constexpr size_t OFF_OFFS = OFF_CNT + (size_t)CPAD * 4;           // CPAD int
constexpr size_t OFF_CUR  = OFF_OFFS+ (size_t)CPAD * 4;           // CPAD int (unused now)
constexpr size_t OFF_ROWL = OFF_CUR + (size_t)CPAD * 4;           // B int

typedef short bf16x8 __attribute__((ext_vector_type(8)));
typedef float f32x4  __attribute__((ext_vector_type(4)));

// fp32 -> bf16 round-to-nearest-even
__device__ __forceinline__ unsigned short f2bf(float f) {
    unsigned int u = __float_as_uint(f);
    return (unsigned short)((u + 0x7FFFu + ((u >> 16) & 1u)) >> 16);
}

__device__ __forceinline__ void cvt8(const float4& a, const float4& b, unsigned short* dst) {
    union { unsigned short u[8]; bf16x8 v; } r;
    r.u[0] = f2bf(a.x); r.u[1] = f2bf(a.y); r.u[2] = f2bf(a.z); r.u[3] = f2bf(a.w);
    r.u[4] = f2bf(b.x); r.u[5] = f2bf(b.y); r.u[6] = f2bf(b.z); r.u[7] = f2bf(b.w);
    *(bf16x8*)dst = r.v;
}

__device__ __forceinline__ ushort4 f2bf4(const float4& a) {
    ushort4 r;
    r.x = f2bf(a.x); r.y = f2bf(a.y); r.z = f2bf(a.z); r.w = f2bf(a.w);
    return r;
}

// async global->LDS, 16B/lane; lds dst = wave-uniform base (+lane*16 implied by HW)
__device__ __forceinline__ void async16(const unsigned short* g, unsigned short* l) {
    __builtin_amdgcn_global_load_lds(
        (const __attribute__((address_space(1))) void*)g,
        (__attribute__((address_space(3))) void*)l,
        16, 0, 0);
}

// ---- 1. fused prep: blocks 0..63 convert W1,W2->bf16 + zero T,Z;
//         block 64 does hist+scan+scatter (counting sort) entirely in one block ----
__global__ __launch_bounds__(1024)
void prep_kernel(const float* __restrict__ W1, const float* __restrict__ W2,
                 unsigned short* __restrict__ Wb,
                 float* __restrict__ T, float* __restrict__ Z,
                 const int* __restrict__ label,
                 int* __restrict__ cnt, int* __restrict__ offs,
                 int* __restrict__ rowlist) {
    __shared__ int hA[1024];
    __shared__ int hB[1024];

    if (blockIdx.x < 64) {
        int lin = blockIdx.x * 1024 + threadIdx.x;   // 0..65535
        int i = lin * 8;
        const float* src = (i < D_OUT * D_IN) ? (W1 + i) : (W2 + (i - D_OUT * D_IN));
        float4 a = *(const float4*)(src);
        float4 b = *(const float4*)(src + 4);
        cvt8(a, b, Wb + i);
        if (lin < D_IN) T[lin] = 0.f;
        *(float4*)(Z + (size_t)lin * 4) = float4{0.f, 0.f, 0.f, 0.f};  // 65536*4 floats = CPAD*D_OUT
        return;
    }

    // ---- block 64: single-block counting-sort prep ----
    int t = threadIdx.x;
    hA[t] = 0;
    __syncthreads();
    int lab[16];
#pragma unroll
    for (int r = 0; r < 16; ++r) {
        lab[r] = label[t + r * 1024];          // coalesced
        atomicAdd(&hA[lab[r]], 1);             // LDS histogram
    }
    __syncthreads();
    int v = hA[t];
    // Hillis-Steele inclusive scan, ping-pong
    int* src = hA;
    int* dst = hB;
    for (int off = 1; off < 1024; off <<= 1) {
        int sv = src[t];
        if (t >= off) sv += src[t - off];
        dst[t] = sv;
        __syncthreads();
        int* tmp = src; src = dst; dst = tmp;
    }
    int excl = src[t] - v;                     // exclusive prefix
    cnt[t]  = v;
    offs[t] = excl;
    dst[t]  = excl;                            // dst buffer = cursor
    __syncthreads();
#pragma unroll
    for (int r = 0; r < 16; ++r) {
        int p = atomicAdd(&dst[lab[r]], 1);
        rowlist[p] = t + r * 1024;
    }
}

// ---- 2. per-class fp32 column sums of x; emits xb = bf16(x) (no T atomics!) ----
__global__ void segsum_kernel(const float* __restrict__ x,
                              const int* __restrict__ offs,
                              const int* __restrict__ cnt,
                              const int* __restrict__ rowlist,
                              float* __restrict__ s,
                              unsigned short* __restrict__ xb) {
    int c = blockIdx.x;            // 0..1023
    int col = threadIdx.x * 4;
    float4 acc = {0.f, 0.f, 0.f, 0.f};
    if (c < NCLS) {
        int o = offs[c], n = cnt[c];
        int r = 0;
        // 8-row unroll: 32 KB of gather loads in flight per block
        for (; r + 8 <= n; r += 8) {
            int idx[8];
#pragma unroll
            for (int u = 0; u < 8; ++u) idx[u] = rowlist[o + r + u];
            float4 v[8];
#pragma unroll
            for (int u = 0; u < 8; ++u)
                v[u] = *(const float4*)(x + (size_t)idx[u] * D_IN + col);
#pragma unroll
            for (int u = 0; u < 8; ++u)
                *(ushort4*)(xb + (size_t)idx[u] * D_IN + col) = f2bf4(v[u]);
#pragma unroll
            for (int u = 0; u < 8; ++u) {
                acc.x += v[u].x; acc.y += v[u].y; acc.z += v[u].z; acc.w += v[u].w;
            }
        }
        for (; r + 4 <= n; r += 4) {
            int i0 = rowlist[o + r + 0];
            int i1 = rowlist[o + r + 1];
            int i2 = rowlist[o + r + 2];
            int i3 = rowlist[o + r + 3];
            float4 v0 = *(const float4*)(x + (size_t)i0 * D_IN + col);
            float4 v1 = *(const float4*)(x + (size_t)i1 * D_IN + col);
            float4 v2 = *(const float4*)(x + (size_t)i2 * D_IN + col);
            float4 v3 = *(const float4*)(x + (size_t)i3 * D_IN + col);
            *(ushort4*)(xb + (size_t)i0 * D_IN + col) = f2bf4(v0);
            *(ushort4*)(xb + (size_t)i1 * D_IN + col) = f2bf4(v1);
            *(ushort4*)(xb + (size_t)i2 * D_IN + col) = f2bf4(v2);
            *(ushort4*)(xb + (size_t)i3 * D_IN + col) = f2bf4(v3);
            acc.x += (v0.x + v1.x) + (v2.x + v3.x);
            acc.y += (v0.y + v1.y) + (v2.y + v3.y);
            acc.z += (v0.z + v1.z) + (v2.z + v3.z);
            acc.w += (v0.w + v1.w) + (v2.w + v3.w);
        }
        for (; r < n; ++r) {
            int i0 = rowlist[o + r];
            float4 v = *(const float4*)(x + (size_t)i0 * D_IN + col);
            *(ushort4*)(xb + (size_t)i0 * D_IN + col) = f2bf4(v);
            acc.x += v.x; acc.y += v.y; acc.z += v.z; acc.w += v.w;
        }
    }
    *(float4*)(s + (size_t)c * D_IN + col) = acc;
}

// ---- 3. T = column-sum of s (64 blocks -> only 64 atomics/address) ----
__global__ void tsum_kernel(const float* __restrict__ s, float* __restrict__ T) {
    int col = threadIdx.x * 4;
    int c0 = blockIdx.x * 16;
    float4 acc = {0.f, 0.f, 0.f, 0.f};
#pragma unroll 4
    for (int c = 0; c < 16; ++c) {
        float4 v = *(const float4*)(s + (size_t)(c0 + c) * D_IN + col);
        acc.x += v.x; acc.y += v.y; acc.z += v.z; acc.w += v.w;
    }
    atomicAdd(&T[col + 0], acc.x);
    atomicAdd(&T[col + 1], acc.y);
    atomicAdd(&T[col + 2], acc.z);
    atomicAdd(&T[col + 3], acc.w);
}

// ---- 4. Z[c] += ((T - s_c)/d_c) @ W2^T (+ b2 in chunk 0); 64x64 tile, K-split x4 ----
__global__ __launch_bounds__(256)
void meanz_kernel(const float* __restrict__ s,
                  const float* __restrict__ T,
                  const int* __restrict__ cnt,
                  const unsigned short* __restrict__ Wb,
                  const float* __restrict__ b2,
                  float* __restrict__ Z) {
    __shared__ unsigned short As[64 * 32];
    __shared__ unsigned short Bs[64 * 32];

    const int tid  = threadIdx.x;
    const int wave = tid >> 6;
    const int lane = tid & 63;
    const int quad = lane >> 4;
    const int l16  = lane & 15;
    const int bm   = blockIdx.x * 64;   // class base
    const int bn   = blockIdx.y * 64;   // out-col base
    const int kb   = blockIdx.z * 256;  // K chunk
    const int wm   = (wave >> 1) * 32;
    const int wn   = (wave & 1) * 32;

    const int arow = tid >> 2;          // 0..63
    const int akc  = (tid & 3) * 8;     // 0,8,16,24

    const int cls = bm + arow;
    const int d   = B - cnt[cls];
    const float scale = (d > 0) ? 1.f / (float)d : 0.f;
    const float* sp = s + (size_t)cls * D_IN + akc;
    const float* tp = T + akc;

    // B async chunk mapping: 1 chunk of 16B per thread
    const int bidx = wave * 64 + lane;
    const int brow = bidx >> 2;
    const int bkc  = (bidx & 3) * 8;
    const unsigned short* bp = Wb + (size_t)(256 + bn + brow) * D_IN + bkc;

    f32x4 acc[2][2] = {};

    for (int k0 = kb; k0 < kb + 256; k0 += 32) {
        float4 s0 = *(const float4*)(sp + k0);
        float4 s1 = *(const float4*)(sp + k0 + 4);
        float4 t0 = *(const float4*)(tp + k0);
        float4 t1 = *(const float4*)(tp + k0 + 4);
        __syncthreads();   // previous iteration's frag reads complete
        async16(bp + k0, Bs + wave * 512);
        float4 m0 = {(t0.x - s0.x) * scale, (t0.y - s0.y) * scale,
                     (t0.z - s0.z) * scale, (t0.w - s0.w) * scale};
        float4 m1 = {(t1.x - s1.x) * scale, (t1.y - s1.y) * scale,
                     (t1.z - s1.z) * scale, (t1.w - s1.w) * scale};
        cvt8(m0, m1, As + arow * 32 + akc);
        __syncthreads();   // drains vmcnt (async B) + lgkm (A writes)

        bf16x8 af[2], bfr[2];
#pragma unroll
        for (int t = 0; t < 2; ++t) {
            af[t]  = *(const bf16x8*)&As[(wm + t * 16 + l16) * 32 + quad * 8];
            bfr[t] = *(const bf16x8*)&Bs[(wn + t * 16 + l16) * 32 + quad * 8];
        }
#pragma unroll
        for (int i = 0; i < 2; ++i)
#pragma unroll
            for (int j = 0; j < 2; ++j)
                acc[i][j] = __builtin_amdgcn_mfma_f32_16x16x32_bf16(af[i], bfr[j], acc[i][j], 0, 0, 0);
    }

    const bool addb = (blockIdx.z == 0);
#pragma unroll
    for (int j = 0; j < 2; ++j) {
        const int n = bn + wn + j * 16 + l16;
        const float bias = addb ? b2[n] : 0.f;
#pragma unroll
        for (int i = 0; i < 2; ++i)
#pragma unroll
            for (int r = 0; r < 4; ++r) {
                const int c = bm + wm + i * 16 + quad * 4 + r;
                atomicAdd(&Z[(size_t)c * D_OUT + n], acc[i][j][r] + bias);
            }
    }
}

// ---- 5. out = xb @ W1b^T + b1 + Z[label] ; 128x64 tile, BK=64, all-async staging ----
// LDS holds the two K=32 slices in separate halves ([2][rows][32]) so the row
// stride stays 64 B => same conflict-free ds_read_b128 pattern as the 64x64 version.
__global__ __launch_bounds__(256)
void gemm1_kernel(const unsigned short* __restrict__ xb,
                  const unsigned short* __restrict__ Wb,
                  const float* __restrict__ b1,
                  const float* __restrict__ Z,
                  const int* __restrict__ label,
                  float* __restrict__ out) {
    __shared__ unsigned short As[2][128][32];   // 16 KB
    __shared__ unsigned short Bs[2][64][32];    //  8 KB

    const int tid  = threadIdx.x;
    const int wave = tid >> 6;
    const int lane = tid & 63;
    const int quad = lane >> 4;
    const int l16  = lane & 15;
    const int bm   = blockIdx.x * 128;
    const int bn   = blockIdx.y * 64;
    const int wm   = (wave >> 1) * 64;   // 2x2 wave grid: each wave owns 64x32
    const int wn   = (wave & 1) * 32;

    // A staging: 1024 chunks of 16B (4 rounds x 256 threads)
    //   chunk d: h=d>>9 (K-half), r=(d>>2)&127 (row), c=d&3 (16B col within half)
    const unsigned short* aps[4];
#pragma unroll
    for (int rr = 0; rr < 4; ++rr) {
        int dd = rr * 256 + tid;
        int h = dd >> 9, r = (dd >> 2) & 127, c = dd & 3;
        aps[rr] = xb + (size_t)(bm + r) * D_IN + h * 32 + c * 8;
    }
    // B staging: 512 chunks (2 rounds x 256 threads)
    const unsigned short* bps[2];
#pragma unroll
    for (int rr = 0; rr < 2; ++rr) {
        int dd = rr * 256 + tid;
        int h = dd >> 8, r = (dd >> 2) & 63, c = dd & 3;
        bps[rr] = Wb + (size_t)(bn + r) * D_IN + h * 32 + c * 8;
    }

    f32x4 acc[4][2] = {};

    for (int k0 = 0; k0 < D_IN; k0 += 64) {
        __syncthreads();   // previous iteration's frag reads complete
#pragma unroll
        for (int rr = 0; rr < 4; ++rr)
            async16(aps[rr] + k0, &As[0][0][0] + rr * 2048 + wave * 512);
#pragma unroll
        for (int rr = 0; rr < 2; ++rr)
            async16(bps[rr] + k0, &Bs[0][0][0] + rr * 2048 + wave * 512);
        __syncthreads();   // vmcnt drain before frag reads

#pragma unroll
        for (int ks = 0; ks < 2; ++ks) {
            bf16x8 af[4], bfr[2];
#pragma unroll
            for (int i = 0; i < 4; ++i)
                af[i] = *(const bf16x8*)&As[ks][wm + i * 16 + l16][quad * 8];
#pragma unroll
            for (int j = 0; j < 2; ++j)
                bfr[j] = *(const bf16x8*)&Bs[ks][wn + j * 16 + l16][quad * 8];
#pragma unroll
            for (int i = 0; i < 4; ++i)
#pragma unroll
                for (int j = 0; j < 2; ++j)
                    acc[i][j] = __builtin_amdgcn_mfma_f32_16x16x32_bf16(af[i], bfr[j], acc[i][j], 0, 0, 0);
        }
    }

    // epilogue: out[m][n] = acc + b1[n] + Z[label[m]][n]
    int zrow[4][4];
#pragma unroll
    for (int i = 0; i < 4; ++i)
#pragma unroll
        for (int r = 0; r < 4; ++r)
            zrow[i][r] = label[bm + wm + i * 16 + quad * 4 + r] * D_OUT;

#pragma unroll
    for (int j = 0; j < 2; ++j) {
        const int n = bn + wn + j * 16 + l16;
        const float bias = b1[n];
#pragma unroll
        for (int i = 0; i < 4; ++i)
#pragma unroll
            for (int r = 0; r < 4; ++r) {
                const int m = bm + wm + i * 16 + quad * 4 + r;
                out[(size_t)m * D_OUT + n] = acc[i][j][r] + bias + Z[zrow[i][r] + n];
            }
    }
}

// ---------------- launcher ----------------
extern "C" void kernel_launch(void* const* d_in, const int* in_sizes, int n_in,
                              void* d_out, int out_size, void* d_ws, size_t ws_size,
                              hipStream_t stream) {
    const float* x    = (const float*)d_in[0];
    const int*   lab  = (const int*)d_in[1];
    const float* W1_w = (const float*)d_in[2];
    const float* W1_b = (const float*)d_in[3];
    const float* W2_w = (const float*)d_in[4];
    const float* W2_b = (const float*)d_in[5];
    float* out = (float*)d_out;

    char* ws = (char*)d_ws;
    unsigned short* xb = (unsigned short*)(ws + OFF_XB);
    unsigned short* Wb = (unsigned short*)(ws + OFF_WB);
    float* s   = (float*)(ws + OFF_S);
    float* Z   = (float*)(ws + OFF_Z);
    float* T   = (float*)(ws + OFF_T);
    int* cnt     = (int*)(ws + OFF_CNT);
    int* offs    = (int*)(ws + OFF_OFFS);
    int* rowlist = (int*)(ws + OFF_ROWL);

    // 1. fused: W convert + zero T/Z (blocks 0-63) || hist+scan+scatter (block 64)
    prep_kernel<<<65, 1024, 0, stream>>>(W1_w, W2_w, Wb, T, Z, lab, cnt, offs, rowlist);
    // 2. per-class sums + xb emit
    segsum_kernel<<<CPAD, 256, 0, stream>>>(x, offs, cnt, rowlist, s, xb);
    // 3. grand total (64 atomics/address only)
    tsum_kernel<<<64, 256, 0, stream>>>(s, T);
    // 4. Z table (K-split x4, 256 blocks)
    dim3 zgrid(CPAD / 64, D_OUT / 64, 4);
    meanz_kernel<<<zgrid, 256, 0, stream>>>(s, T, cnt, Wb, W2_b, Z);
    // 5. main GEMM, 128x64 tile, BK=64
    dim3 ggrid(B / 128, D_OUT / 64);
    gemm1_kernel<<<ggrid, 256, 0, stream>>>(xb, Wb, W1_b, Z, lab, out);
}